// Round 2
// baseline (37869.559 us; speedup 1.0000x reference)
//
#include <hip/hip_runtime.h>
#include <math.h>

// Griffin-Lim inversion of a log-magnitude spectrogram.
// B=128, F=256 frames, 128 rfft bins (N_FFT=254), HOP=64, 50 iterations.
// DFT as GEMM (fp32 vector FMA). Overlap-add fused into gemm1's A-staging.

#define B_SZ 128
#define NFRM 256
#define BINS 128
#define NFFT 254
#define HOPS 64
#define OUTL 16574
#define AUD  16384
#define WFS  16576
#define GL_ITERS 50
#define MAXV 69.37411499023438f
#define PI2f 6.2831853071795864f

// ---------------------------------------------------------------- tables ----
__global__ void tables_k(float* __restrict__ Wf, float* __restrict__ Wi,
                         unsigned* __restrict__ gmax) {
  int tid = blockIdx.x * blockDim.x + threadIdx.x;
  int stride = gridDim.x * blockDim.x;
  if (blockIdx.x == 0 && threadIdx.x == 0) *gmax = 0u;

  for (int i = tid; i < 256 * 256; i += stride) {
    int n = i >> 8, j = i & 255, k = j >> 1;
    float v = 0.f;
    if (n < NFFT) {
      int m = (k * n) % NFFT;
      float ang = PI2f * (float)m / (float)NFFT;
      float wn = 0.5f - 0.5f * cosf(PI2f * (float)n / (float)NFFT);
      v = wn * ((j & 1) ? -sinf(ang) : cosf(ang));
    }
    Wf[i] = v;
  }
  for (int i = tid; i < 256 * 256; i += stride) {
    int j = i >> 8, n = i & 255, k = j >> 1;
    float v = 0.f;
    if (n < NFFT) {
      int m = (k * n) % NFFT;
      float ang = PI2f * (float)m / (float)NFFT;
      float wn = 0.5f - 0.5f * cosf(PI2f * (float)n / (float)NFFT);
      float d = 0.f;
      int p = n & 63;
      for (int q = 0; q < 4; ++q) {
        int nn = p + 64 * q;
        if (nn < NFFT) { float w = 0.5f - 0.5f * cosf(PI2f * (float)nn / (float)NFFT); d += w * w; }
      }
      float sw = wn / d;
      float ak = (k == 0 || k == BINS - 1) ? 1.f : 2.f;
      v = sw * (ak / (float)NFFT) * ((j & 1) ? -sinf(ang) : cosf(ang));
    }
    Wi[i] = v;
  }
}

// ------------------------------------------------------------------- mag ----
__global__ void mag_k(const float* __restrict__ x, float* __restrict__ mag,
                      float* __restrict__ S) {
  int i = blockIdx.x * 256 + threadIdx.x;          // B*F*BINS = 4194304 exact
  float v = expf(5.f * (x[i] - 1.f)) * MAXV;
  mag[i] = v;
  size_t m = (size_t)(i >> 7);
  int k = i & 127;
  S[(m << 8) + 2 * k]     = v;
  S[(m << 8) + 2 * k + 1] = 0.f;
}

// ---------------------------------------------------- GEMM1: OA+STFT+mod ----
// Block = (batch b, 32 frames starting at f0). A-tile built by overlap-adding
// FR directly into LDS (no wf round-trip). 8 rows x 4 cols per thread.
__global__ __launch_bounds__(256, 4) void gemm1_k(const float* __restrict__ FR,
    const float* __restrict__ Wf, const float* __restrict__ mag,
    float* __restrict__ S) {
  __shared__ __align__(16) float wfs[2240];        // (32-1)*64 + 254 = 2238 (+2 pad)
  __shared__ __align__(16) float Bl[2][16][256];
  int blk = blockIdx.x;
  int b = blk >> 3, f0 = (blk & 7) * 32;
  int tid = threadIdx.x, lane = tid & 63, wv = tid >> 6;
  const float* FRb = FR + ((size_t)b << 16);

  // fused overlap-add: wfs[i] = wf[f0*64 + i]
  for (int i = tid; i < 2238; i += 256) {
    int t = f0 * 64 + i;
    int f_hi = t >> 6; if (f_hi > NFRM - 1) f_hi = NFRM - 1;
    int f_lo = (t >= NFFT) ? (((t - NFFT) >> 6) + 1) : 0;
    float s = 0.f;
    for (int f = f_lo; f <= f_hi; ++f) s += FRb[(f << 8) + t - (f << 6)];
    wfs[i] = s;
  }
  if (tid == 0) { wfs[2238] = 0.f; wfs[2239] = 0.f; }   // avoid NaN*0 on zero B rows

  float acc[8][4];
#pragma unroll
  for (int i = 0; i < 8; ++i) { acc[i][0] = acc[i][1] = acc[i][2] = acc[i][3] = 0.f; }

  {  // prologue: stage chunk 0
    const float4* src = (const float4*)Wf;
    float4* dst = (float4*)&Bl[0][0][0];
    float4 r0 = src[tid], r1 = src[tid + 256], r2 = src[tid + 512], r3 = src[tid + 768];
    dst[tid] = r0; dst[tid + 256] = r1; dst[tid + 512] = r2; dst[tid + 768] = r3;
  }
  __syncthreads();

  int c = 0;
  for (int kk = 0; kk < 256; kk += 16) {
    float4 p0, p1, p2, p3;
    bool more = (kk + 16) < 256;
    if (more) {
      const float4* src = (const float4*)(Wf + ((size_t)(kk + 16) << 8));
      p0 = src[tid]; p1 = src[tid + 256]; p2 = src[tid + 512]; p3 = src[tid + 768];
    }
#pragma unroll
    for (int t4 = 0; t4 < 16; t4 += 4) {
      float4 b0 = *(const float4*)&Bl[c][t4 + 0][lane << 2];
      float4 b1 = *(const float4*)&Bl[c][t4 + 1][lane << 2];
      float4 b2 = *(const float4*)&Bl[c][t4 + 2][lane << 2];
      float4 b3 = *(const float4*)&Bl[c][t4 + 3][lane << 2];
#pragma unroll
      for (int i2 = 0; i2 < 8; ++i2) {
        float4 a4 = *(const float4*)&wfs[((wv << 3) + i2) * HOPS + kk + t4];  // broadcast
        acc[i2][0] += a4.x * b0.x + a4.y * b1.x + a4.z * b2.x + a4.w * b3.x;
        acc[i2][1] += a4.x * b0.y + a4.y * b1.y + a4.z * b2.y + a4.w * b3.y;
        acc[i2][2] += a4.x * b0.z + a4.y * b1.z + a4.z * b2.z + a4.w * b3.z;
        acc[i2][3] += a4.x * b0.w + a4.y * b1.w + a4.z * b2.w + a4.w * b3.w;
      }
    }
    if (more) {
      float4* dst = (float4*)&Bl[c ^ 1][0][0];
      dst[tid] = p0; dst[tid + 256] = p1; dst[tid + 512] = p2; dst[tid + 768] = p3;
    }
    __syncthreads();
    c ^= 1;
  }

  // spec = mag * X / |X|
#pragma unroll
  for (int i2 = 0; i2 < 8; ++i2) {
    int fr = f0 + (wv << 3) + i2;
    const float2* mp = (const float2*)(mag + ((size_t)b * NFRM + fr) * BINS);
    float2 mg = mp[lane];
    float re0 = acc[i2][0], im0 = acc[i2][1], re1 = acc[i2][2], im1 = acc[i2][3];
    float s0 = re0 * re0 + im0 * im0;
    float s1 = re1 * re1 + im1 * im1;
    if (s0 == 0.f) { re0 = 1.f; s0 = 1.f; }
    if (s1 == 0.f) { re1 = 1.f; s1 = 1.f; }
    float r0 = mg.x * rsqrtf(s0);
    float r1 = mg.y * rsqrtf(s1);
    float4 o = make_float4(re0 * r0, im0 * r0, re1 * r1, im1 * r1);
    *(float4*)(S + (((size_t)b * NFRM + fr) << 8) + (lane << 2)) = o;
  }
}

// --------------------------------------------------------- GEMM2: iSTFT -----
__global__ __launch_bounds__(256, 4) void gemm2_k(const float* __restrict__ S,
    const float* __restrict__ Wi, float* __restrict__ FR) {
  __shared__ __align__(16) float Al[2][32][16];
  __shared__ __align__(16) float Bl[2][16][256];
  int row0 = blockIdx.x * 32;
  int tid = threadIdx.x, lane = tid & 63, wv = tid >> 6;

  float acc[8][4];
#pragma unroll
  for (int i = 0; i < 8; ++i) { acc[i][0] = acc[i][1] = acc[i][2] = acc[i][3] = 0.f; }

  {  // prologue: stage chunk 0
    const float4* src = (const float4*)Wi;
    float4* dst = (float4*)&Bl[0][0][0];
    float4 r0 = src[tid], r1 = src[tid + 256], r2 = src[tid + 512], r3 = src[tid + 768];
    dst[tid] = r0; dst[tid + 256] = r1; dst[tid + 512] = r2; dst[tid + 768] = r3;
    if (tid < 128) {
      int r = tid >> 2, c4 = (tid & 3) << 2;
      *(float4*)&Al[0][r][c4] = *(const float4*)(S + ((size_t)(row0 + r) << 8) + c4);
    }
  }
  __syncthreads();

  int c = 0;
  for (int kk = 0; kk < 256; kk += 16) {
    float4 p0, p1, p2, p3, pa;
    bool more = (kk + 16) < 256;
    if (more) {
      const float4* src = (const float4*)(Wi + ((size_t)(kk + 16) << 8));
      p0 = src[tid]; p1 = src[tid + 256]; p2 = src[tid + 512]; p3 = src[tid + 768];
      if (tid < 128) {
        int r = tid >> 2, c4 = (tid & 3) << 2;
        pa = *(const float4*)(S + ((size_t)(row0 + r) << 8) + kk + 16 + c4);
      }
    }
#pragma unroll
    for (int t4 = 0; t4 < 16; t4 += 4) {
      float4 b0 = *(const float4*)&Bl[c][t4 + 0][lane << 2];
      float4 b1 = *(const float4*)&Bl[c][t4 + 1][lane << 2];
      float4 b2 = *(const float4*)&Bl[c][t4 + 2][lane << 2];
      float4 b3 = *(const float4*)&Bl[c][t4 + 3][lane << 2];
#pragma unroll
      for (int i2 = 0; i2 < 8; ++i2) {
        float4 a4 = *(const float4*)&Al[c][(wv << 3) + i2][t4];               // broadcast
        acc[i2][0] += a4.x * b0.x + a4.y * b1.x + a4.z * b2.x + a4.w * b3.x;
        acc[i2][1] += a4.x * b0.y + a4.y * b1.y + a4.z * b2.y + a4.w * b3.y;
        acc[i2][2] += a4.x * b0.z + a4.y * b1.z + a4.z * b2.z + a4.w * b3.z;
        acc[i2][3] += a4.x * b0.w + a4.y * b1.w + a4.z * b2.w + a4.w * b3.w;
      }
    }
    if (more) {
      float4* dst = (float4*)&Bl[c ^ 1][0][0];
      dst[tid] = p0; dst[tid + 256] = p1; dst[tid + 512] = p2; dst[tid + 768] = p3;
      if (tid < 128) {
        int r = tid >> 2, c4 = (tid & 3) << 2;
        *(float4*)&Al[c ^ 1][r][c4] = pa;
      }
    }
    __syncthreads();
    c ^= 1;
  }
#pragma unroll
  for (int i2 = 0; i2 < 8; ++i2) {
    *(float4*)(FR + (((size_t)(row0 + (wv << 3) + i2)) << 8) + (lane << 2)) =
        make_float4(acc[i2][0], acc[i2][1], acc[i2][2], acc[i2][3]);
  }
}

// ----------------------------------------------------------- overlap-add ----
__global__ void oa_k(const float* __restrict__ FR, float* __restrict__ wf) {
  int b = blockIdx.y, t = blockIdx.x * 256 + threadIdx.x;
  if (t >= OUTL) return;
  int f_hi = t >> 6; if (f_hi > NFRM - 1) f_hi = NFRM - 1;
  int f_lo = (t >= NFFT) ? (((t - NFFT) >> 6) + 1) : 0;
  const float* FRb = FR + ((size_t)b << 16);
  float s = 0.f;
  for (int f = f_lo; f <= f_hi; ++f) s += FRb[(f << 8) + t - (f << 6)];
  wf[(size_t)b * WFS + t] = s;
}

// ------------------------------------------------------------- reductions ---
__global__ void redmax_k(const float* __restrict__ wf, unsigned* __restrict__ gmax) {
  __shared__ float red[16];
  int b = blockIdx.x;
  const float* w = wf + (size_t)b * WFS;
  float v = 0.f;
  for (int t = threadIdx.x; t < OUTL; t += 1024) v = fmaxf(v, fabsf(w[t]));
#pragma unroll
  for (int o = 32; o > 0; o >>= 1) v = fmaxf(v, __shfl_xor(v, o, 64));
  if ((threadIdx.x & 63) == 0) red[threadIdx.x >> 6] = v;
  __syncthreads();
  if (threadIdx.x < 16) {
    v = red[threadIdx.x];
#pragma unroll
    for (int o = 8; o > 0; o >>= 1) v = fmaxf(v, __shfl_xor(v, o, 16));
    if (threadIdx.x == 0) atomicMax(gmax, __float_as_uint(v));
  }
}

__global__ void out_k(const float* __restrict__ wf, const unsigned* __restrict__ gmax,
                      float* __restrict__ out) {
  int b = blockIdx.y, t = blockIdx.x * 256 + threadIdx.x;
  float g = __uint_as_float(*gmax);
  out[(size_t)b * AUD + t] = wf[(size_t)b * WFS + t] / g;
}

// ---------------------------------------------------------------- launch ----
extern "C" void kernel_launch(void* const* d_in, const int* in_sizes, int n_in,
                              void* d_out, int out_size, void* d_ws, size_t ws_size,
                              hipStream_t stream) {
  const float* x = (const float*)d_in[0];

  float* ws  = (float*)d_ws;
  float* wf  = ws;
  float* mag = wf  + (size_t)B_SZ * WFS;
  float* S   = mag + (size_t)B_SZ * NFRM * BINS;
  float* FR  = S   + (size_t)B_SZ * NFRM * 256;
  float* Wf  = FR  + (size_t)B_SZ * NFRM * 256;
  float* Wi  = Wf  + 65536;
  unsigned* gmax = (unsigned*)(Wi + 65536);

  tables_k<<<64, 256, 0, stream>>>(Wf, Wi, gmax);
  mag_k<<<16384, 256, 0, stream>>>(x, mag, S);

  gemm2_k<<<1024, 256, 0, stream>>>(S, Wi, FR);   // initial istft -> FR

  for (int it = 0; it < GL_ITERS; ++it) {
    gemm1_k<<<1024, 256, 0, stream>>>(FR, Wf, mag, S);  // OA fused inside
    gemm2_k<<<1024, 256, 0, stream>>>(S, Wi, FR);
  }

  oa_k<<<dim3(65, B_SZ), 256, 0, stream>>>(FR, wf);     // final OA only
  redmax_k<<<B_SZ, 1024, 0, stream>>>(wf, gmax);
  out_k<<<dim3(64, B_SZ), 256, 0, stream>>>(wf, gmax, (float*)d_out);
}

// Round 3
// 7274.790 us; speedup vs baseline: 5.2056x; 5.2056x over previous
//
#include <hip/hip_runtime.h>
#include <math.h>

// Griffin-Lim inversion of a log-magnitude spectrogram.
// B=128, F=256 frames, 128 rfft bins (N_FFT=254), HOP=64, 50 iterations.
// DFT as GEMM (fp32 vector FMA). Overlap-add fused into gemm1's A-staging.
// B-operand staged global->LDS via __builtin_amdgcn_global_load_lds (async,
// zero VGPR cost), double-buffered, one barrier per K-chunk.

#define B_SZ 128
#define NFRM 256
#define BINS 128
#define NFFT 254
#define HOPS 64
#define OUTL 16574
#define AUD  16384
#define WFS  16576
#define GL_ITERS 50
#define MAXV 69.37411499023438f
#define PI2f 6.2831853071795864f

__device__ __forceinline__ void gload_lds16(float* lds_dst, const float* gsrc) {
  // HW: LDS write addr = wave-uniform lds_dst + lane*16B; global src is per-lane.
  __builtin_amdgcn_global_load_lds(
      (const __attribute__((address_space(1))) unsigned int*)gsrc,
      (__attribute__((address_space(3))) unsigned int*)lds_dst,
      16, 0, 0);
}

// ---------------------------------------------------------------- tables ----
__global__ void tables_k(float* __restrict__ Wf, float* __restrict__ Wi,
                         unsigned* __restrict__ gmax) {
  int tid = blockIdx.x * blockDim.x + threadIdx.x;
  int stride = gridDim.x * blockDim.x;
  if (blockIdx.x == 0 && threadIdx.x == 0) *gmax = 0u;

  for (int i = tid; i < 256 * 256; i += stride) {
    int n = i >> 8, j = i & 255, k = j >> 1;
    float v = 0.f;
    if (n < NFFT) {
      int m = (k * n) % NFFT;
      float ang = PI2f * (float)m / (float)NFFT;
      float wn = 0.5f - 0.5f * cosf(PI2f * (float)n / (float)NFFT);
      v = wn * ((j & 1) ? -sinf(ang) : cosf(ang));
    }
    Wf[i] = v;
  }
  for (int i = tid; i < 256 * 256; i += stride) {
    int j = i >> 8, n = i & 255, k = j >> 1;
    float v = 0.f;
    if (n < NFFT) {
      int m = (k * n) % NFFT;
      float ang = PI2f * (float)m / (float)NFFT;
      float wn = 0.5f - 0.5f * cosf(PI2f * (float)n / (float)NFFT);
      float d = 0.f;
      int p = n & 63;
      for (int q = 0; q < 4; ++q) {
        int nn = p + 64 * q;
        if (nn < NFFT) { float w = 0.5f - 0.5f * cosf(PI2f * (float)nn / (float)NFFT); d += w * w; }
      }
      float sw = wn / d;
      float ak = (k == 0 || k == BINS - 1) ? 1.f : 2.f;
      v = sw * (ak / (float)NFFT) * ((j & 1) ? -sinf(ang) : cosf(ang));
    }
    Wi[i] = v;
  }
}

// ------------------------------------------------------------------- mag ----
__global__ void mag_k(const float* __restrict__ x, float* __restrict__ mag,
                      float* __restrict__ S) {
  int i = blockIdx.x * 256 + threadIdx.x;          // B*F*BINS = 4194304 exact
  float v = expf(5.f * (x[i] - 1.f)) * MAXV;
  mag[i] = v;
  size_t m = (size_t)(i >> 7);
  int k = i & 127;
  S[(m << 8) + 2 * k]     = v;
  S[(m << 8) + 2 * k + 1] = 0.f;
}

// ---------------------------------------------------- GEMM1: OA+STFT+mod ----
// Block = (batch b, 32 frames from f0). A built by overlap-adding FR into LDS.
// 8 rows x 4 cols per thread.
__global__ __launch_bounds__(256) void gemm1_k(const float* __restrict__ FR,
    const float* __restrict__ Wf, const float* __restrict__ mag,
    float* __restrict__ S) {
  __shared__ __align__(16) float wfs[2240];        // (32-1)*64 + 254 = 2238 (+2 pad)
  __shared__ __align__(16) float Bl[2][16][256];
  int blk = blockIdx.x;
  int b = blk >> 3, f0 = (blk & 7) * 32;
  int tid = threadIdx.x, lane = tid & 63, wv = tid >> 6;
  const float* FRb = FR + ((size_t)b << 16);

  // async-stage chunk 0 of Wf
#pragma unroll
  for (int r = 0; r < 4; ++r) {
    int m = (r << 2) + wv;
    gload_lds16(&Bl[0][m][0], Wf + ((size_t)m << 8) + (lane << 2));
  }

  // fused overlap-add: wfs[i] = wf[f0*64 + i]
  for (int i = tid; i < 2238; i += 256) {
    int t = f0 * 64 + i;
    int f_hi = t >> 6; if (f_hi > NFRM - 1) f_hi = NFRM - 1;
    int f_lo = (t >= NFFT) ? (((t - NFFT) >> 6) + 1) : 0;
    float s = 0.f;
    for (int f = f_lo; f <= f_hi; ++f) s += FRb[(f << 8) + t - (f << 6)];
    wfs[i] = s;
  }
  if (tid == 0) { wfs[2238] = 0.f; wfs[2239] = 0.f; }   // K padded; Wf rows 254/255 zero

  float acc[8][4];
#pragma unroll
  for (int i = 0; i < 8; ++i) { acc[i][0] = acc[i][1] = acc[i][2] = acc[i][3] = 0.f; }

  __syncthreads();                                  // chunk0 + wfs ready

  int c = 0;
  for (int kk = 0; kk < 256; kk += 16) {
    if (kk + 16 < 256) {                            // async-stage next chunk
#pragma unroll
      for (int r = 0; r < 4; ++r) {
        int m = (r << 2) + wv;
        gload_lds16(&Bl[c ^ 1][m][0], Wf + ((size_t)(kk + 16 + m) << 8) + (lane << 2));
      }
    }
#pragma unroll
    for (int t4 = 0; t4 < 16; t4 += 4) {
      float4 b0 = *(const float4*)&Bl[c][t4 + 0][lane << 2];
      float4 b1 = *(const float4*)&Bl[c][t4 + 1][lane << 2];
      float4 b2 = *(const float4*)&Bl[c][t4 + 2][lane << 2];
      float4 b3 = *(const float4*)&Bl[c][t4 + 3][lane << 2];
#pragma unroll
      for (int i2 = 0; i2 < 8; ++i2) {
        float4 a4 = *(const float4*)&wfs[((wv << 3) + i2) * HOPS + kk + t4];  // broadcast
        acc[i2][0] += a4.x * b0.x + a4.y * b1.x + a4.z * b2.x + a4.w * b3.x;
        acc[i2][1] += a4.x * b0.y + a4.y * b1.y + a4.z * b2.y + a4.w * b3.y;
        acc[i2][2] += a4.x * b0.z + a4.y * b1.z + a4.z * b2.z + a4.w * b3.z;
        acc[i2][3] += a4.x * b0.w + a4.y * b1.w + a4.z * b2.w + a4.w * b3.w;
      }
    }
    __syncthreads();                                // drains vmcnt -> next buf ready
    c ^= 1;
  }

  // spec = mag * X / |X|   (lane owns bins 2*lane, 2*lane+1)
#pragma unroll
  for (int i2 = 0; i2 < 8; ++i2) {
    int fr = f0 + (wv << 3) + i2;
    const float2* mp = (const float2*)(mag + ((size_t)b * NFRM + fr) * BINS);
    float2 mg = mp[lane];
    float re0 = acc[i2][0], im0 = acc[i2][1], re1 = acc[i2][2], im1 = acc[i2][3];
    float s0 = re0 * re0 + im0 * im0;
    float s1 = re1 * re1 + im1 * im1;
    if (s0 == 0.f) { re0 = 1.f; s0 = 1.f; }
    if (s1 == 0.f) { re1 = 1.f; s1 = 1.f; }
    float r0 = mg.x * rsqrtf(s0);
    float r1 = mg.y * rsqrtf(s1);
    float4 o = make_float4(re0 * r0, im0 * r0, re1 * r1, im1 * r1);
    *(float4*)(S + (((size_t)b * NFRM + fr) << 8) + (lane << 2)) = o;
  }
}

// --------------------------------------------------------- GEMM2: iSTFT -----
__global__ __launch_bounds__(256) void gemm2_k(const float* __restrict__ S,
    const float* __restrict__ Wi, float* __restrict__ FR) {
  __shared__ __align__(16) float Al[2][32][16];
  __shared__ __align__(16) float Bl[2][16][256];
  int row0 = blockIdx.x * 32;
  int tid = threadIdx.x, lane = tid & 63, wv = tid >> 6;

  // async-stage chunk 0 (B and A)
#pragma unroll
  for (int r = 0; r < 4; ++r) {
    int m = (r << 2) + wv;
    gload_lds16(&Bl[0][m][0], Wi + ((size_t)m << 8) + (lane << 2));
  }
  if (wv < 2) {
    gload_lds16(&Al[0][wv << 4][0],
                S + ((size_t)(row0 + (wv << 4) + (lane >> 2)) << 8) + ((lane & 3) << 2));
  }

  float acc[8][4];
#pragma unroll
  for (int i = 0; i < 8; ++i) { acc[i][0] = acc[i][1] = acc[i][2] = acc[i][3] = 0.f; }

  __syncthreads();

  int c = 0;
  for (int kk = 0; kk < 256; kk += 16) {
    if (kk + 16 < 256) {
#pragma unroll
      for (int r = 0; r < 4; ++r) {
        int m = (r << 2) + wv;
        gload_lds16(&Bl[c ^ 1][m][0], Wi + ((size_t)(kk + 16 + m) << 8) + (lane << 2));
      }
      if (wv < 2) {
        gload_lds16(&Al[c ^ 1][wv << 4][0],
                    S + ((size_t)(row0 + (wv << 4) + (lane >> 2)) << 8) + kk + 16 + ((lane & 3) << 2));
      }
    }
#pragma unroll
    for (int t4 = 0; t4 < 16; t4 += 4) {
      float4 b0 = *(const float4*)&Bl[c][t4 + 0][lane << 2];
      float4 b1 = *(const float4*)&Bl[c][t4 + 1][lane << 2];
      float4 b2 = *(const float4*)&Bl[c][t4 + 2][lane << 2];
      float4 b3 = *(const float4*)&Bl[c][t4 + 3][lane << 2];
#pragma unroll
      for (int i2 = 0; i2 < 8; ++i2) {
        float4 a4 = *(const float4*)&Al[c][(wv << 3) + i2][t4];               // broadcast
        acc[i2][0] += a4.x * b0.x + a4.y * b1.x + a4.z * b2.x + a4.w * b3.x;
        acc[i2][1] += a4.x * b0.y + a4.y * b1.y + a4.z * b2.y + a4.w * b3.y;
        acc[i2][2] += a4.x * b0.z + a4.y * b1.z + a4.z * b2.z + a4.w * b3.z;
        acc[i2][3] += a4.x * b0.w + a4.y * b1.w + a4.z * b2.w + a4.w * b3.w;
      }
    }
    __syncthreads();
    c ^= 1;
  }
#pragma unroll
  for (int i2 = 0; i2 < 8; ++i2) {
    *(float4*)(FR + (((size_t)(row0 + (wv << 3) + i2)) << 8) + (lane << 2)) =
        make_float4(acc[i2][0], acc[i2][1], acc[i2][2], acc[i2][3]);
  }
}

// ----------------------------------------------------------- overlap-add ----
__global__ void oa_k(const float* __restrict__ FR, float* __restrict__ wf) {
  int b = blockIdx.y, t = blockIdx.x * 256 + threadIdx.x;
  if (t >= OUTL) return;
  int f_hi = t >> 6; if (f_hi > NFRM - 1) f_hi = NFRM - 1;
  int f_lo = (t >= NFFT) ? (((t - NFFT) >> 6) + 1) : 0;
  const float* FRb = FR + ((size_t)b << 16);
  float s = 0.f;
  for (int f = f_lo; f <= f_hi; ++f) s += FRb[(f << 8) + t - (f << 6)];
  wf[(size_t)b * WFS + t] = s;
}

// ------------------------------------------------------------- reductions ---
__global__ void redmax_k(const float* __restrict__ wf, unsigned* __restrict__ gmax) {
  __shared__ float red[16];
  int b = blockIdx.x;
  const float* w = wf + (size_t)b * WFS;
  float v = 0.f;
  for (int t = threadIdx.x; t < OUTL; t += 1024) v = fmaxf(v, fabsf(w[t]));
#pragma unroll
  for (int o = 32; o > 0; o >>= 1) v = fmaxf(v, __shfl_xor(v, o, 64));
  if ((threadIdx.x & 63) == 0) red[threadIdx.x >> 6] = v;
  __syncthreads();
  if (threadIdx.x < 16) {
    v = red[threadIdx.x];
#pragma unroll
    for (int o = 8; o > 0; o >>= 1) v = fmaxf(v, __shfl_xor(v, o, 16));
    if (threadIdx.x == 0) atomicMax(gmax, __float_as_uint(v));
  }
}

__global__ void out_k(const float* __restrict__ wf, const unsigned* __restrict__ gmax,
                      float* __restrict__ out) {
  int b = blockIdx.y, t = blockIdx.x * 256 + threadIdx.x;
  float g = __uint_as_float(*gmax);
  out[(size_t)b * AUD + t] = wf[(size_t)b * WFS + t] / g;
}

// ---------------------------------------------------------------- launch ----
extern "C" void kernel_launch(void* const* d_in, const int* in_sizes, int n_in,
                              void* d_out, int out_size, void* d_ws, size_t ws_size,
                              hipStream_t stream) {
  const float* x = (const float*)d_in[0];

  float* ws  = (float*)d_ws;
  float* wf  = ws;
  float* mag = wf  + (size_t)B_SZ * WFS;
  float* S   = mag + (size_t)B_SZ * NFRM * BINS;
  float* FR  = S   + (size_t)B_SZ * NFRM * 256;
  float* Wf  = FR  + (size_t)B_SZ * NFRM * 256;
  float* Wi  = Wf  + 65536;
  unsigned* gmax = (unsigned*)(Wi + 65536);

  tables_k<<<64, 256, 0, stream>>>(Wf, Wi, gmax);
  mag_k<<<16384, 256, 0, stream>>>(x, mag, S);

  gemm2_k<<<1024, 256, 0, stream>>>(S, Wi, FR);   // initial istft -> FR

  for (int it = 0; it < GL_ITERS; ++it) {
    gemm1_k<<<1024, 256, 0, stream>>>(FR, Wf, mag, S);  // OA fused inside
    gemm2_k<<<1024, 256, 0, stream>>>(S, Wi, FR);
  }

  oa_k<<<dim3(65, B_SZ), 256, 0, stream>>>(FR, wf);     // final OA only
  redmax_k<<<B_SZ, 1024, 0, stream>>>(wf, gmax);
  out_k<<<dim3(64, B_SZ), 256, 0, stream>>>(wf, gmax, (float*)d_out);
}

// Round 5
// 4569.713 us; speedup vs baseline: 8.2871x; 1.5920x over previous
//
#include <hip/hip_runtime.h>
#include <math.h>

// Griffin-Lim inversion, fp32-accurate MFMA edition.
// Both DFT GEMMs on v_mfma_f32_16x16x32_bf16 with 3-term bf16 splits
// (a = ah+am+al exactly represents an fp32; 6 MFMAs capture all products
// down to 2^-26 rel — below fp32 rounding). Splits happen ONCE at the
// producer (OA->LDS in gemm1; epilogue->global S in gemm1), never in the
// K-loop. B tables precomputed in fragment order, read per-lane from L2.

#define B_SZ 128
#define NFRM 256
#define BINS 128
#define NFFT 254
#define HOPS 64
#define OUTL 16574
#define AUD  16384
#define GL_ITERS 50
#define MAXV 69.37411499023438f
#define PI2f 6.2831853071795864f

typedef __attribute__((ext_vector_type(8))) short short8;
typedef __attribute__((ext_vector_type(4))) float f32x4;

__device__ __forceinline__ unsigned short f2bf(float f) {     // RNE f32->bf16
  unsigned u = __float_as_uint(f);
  return (unsigned short)((u + 0x7FFFu + ((u >> 16) & 1u)) >> 16);
}
__device__ __forceinline__ float bf2f(unsigned short h) {
  return __uint_as_float(((unsigned)h) << 16);
}
__device__ __forceinline__ void split3(float v, short* h, short* m, short* l) {
  unsigned short hh = f2bf(v);
  float r1 = v - bf2f(hh);          // exact in fp32
  unsigned short mm = f2bf(r1);
  float r2 = r1 - bf2f(mm);         // exact; ~6 significant bits left
  *h = (short)hh; *m = (short)mm; *l = (short)f2bf(r2);
}
__device__ __forceinline__ void gld16(const void* g, void* l) {
  __builtin_amdgcn_global_load_lds(
      (const __attribute__((address_space(1))) unsigned*)g,
      (__attribute__((address_space(3))) unsigned*)l, 16, 0, 0);
}

// 6-product accumulation, smallest-magnitude terms first
#define MFMA6(ACC, AH, AM, AL, BH, BM, BL)                                   \
  ACC = __builtin_amdgcn_mfma_f32_16x16x32_bf16(AH, BL, ACC, 0, 0, 0);       \
  ACC = __builtin_amdgcn_mfma_f32_16x16x32_bf16(AM, BM, ACC, 0, 0, 0);       \
  ACC = __builtin_amdgcn_mfma_f32_16x16x32_bf16(AL, BH, ACC, 0, 0, 0);       \
  ACC = __builtin_amdgcn_mfma_f32_16x16x32_bf16(AH, BM, ACC, 0, 0, 0);       \
  ACC = __builtin_amdgcn_mfma_f32_16x16x32_bf16(AM, BH, ACC, 0, 0, 0);       \
  ACC = __builtin_amdgcn_mfma_f32_16x16x32_bf16(AH, BH, ACC, 0, 0, 0);

// ---------------------------------------------------------------- tables ----
// Fragment order: tile (kc,nt): lane l elem j <- W[kc*32+(l>>4)*8+j][nt*16+(l&15)]
// flat = (((kc*16+nt)*64)+l)*8 + j. Split into H/M/L bf16 tables.
__global__ void tables_k(short* __restrict__ WfH, short* __restrict__ WfM,
                         short* __restrict__ WfL, short* __restrict__ WiH,
                         short* __restrict__ WiM, short* __restrict__ WiL,
                         unsigned* __restrict__ gmax) {
  int tid = blockIdx.x * blockDim.x + threadIdx.x;
  if (tid == 0) *gmax = 0u;
  if (tid >= 65536) return;
  int idx = tid;
  int j = idx & 7, l = (idx >> 3) & 63, nt = (idx >> 9) & 15, kc = idx >> 13;
  int krow = kc * 32 + ((l >> 4) << 3) + j;
  int ncol = (nt << 4) + (l & 15);
  // gemm1 B: Wf[k=sample][n=spec-col], hann folded in
  float v1 = 0.f;
  if (krow < NFFT) {
    int kk = ncol >> 1;
    int m = (kk * krow) % NFFT;
    float ang = PI2f * (float)m / (float)NFFT;
    float wn = 0.5f - 0.5f * cosf(PI2f * (float)krow / (float)NFFT);
    v1 = wn * ((ncol & 1) ? -sinf(ang) : cosf(ang));
  }
  split3(v1, &WfH[idx], &WfM[idx], &WfL[idx]);
  // gemm2 B: Wi[k=spec-row][n=sample], synth window + ak/254 folded in
  float v2 = 0.f;
  if (ncol < NFFT) {
    int kk = krow >> 1;
    int m = (kk * ncol) % NFFT;
    float ang = PI2f * (float)m / (float)NFFT;
    float wn = 0.5f - 0.5f * cosf(PI2f * (float)ncol / (float)NFFT);
    float d = 0.f;
    int p = ncol & 63;
    for (int q = 0; q < 4; ++q) {
      int nn = p + 64 * q;
      if (nn < NFFT) { float w = 0.5f - 0.5f * cosf(PI2f * (float)nn / (float)NFFT); d += w * w; }
    }
    float sw = wn / d;
    float ak = (kk == 0 || kk == BINS - 1) ? 1.f : 2.f;
    v2 = sw * (ak / (float)NFFT) * ((krow & 1) ? -sinf(ang) : cosf(ang));
  }
  split3(v2, &WiH[idx], &WiM[idx], &WiL[idx]);
}

// -------------------------------------------------------------- initial S ---
// S storage (bf16 rows of 256): 16B chunk c (8 bf16) of row r stored at
// chunk (c&~7)|((c^r)&7)  (XOR-swizzle within aligned 8-chunk groups).
__global__ void initS_k(const float* __restrict__ x, short* __restrict__ Sh,
                        short* __restrict__ Sm, short* __restrict__ Sl) {
  int i = blockIdx.x * 256 + threadIdx.x;          // B*F*BINS = 4194304 exact
  float v = expf(5.f * (x[i] - 1.f)) * MAXV;
  short h, m, l;
  split3(v, &h, &m, &l);
  int mrow = i >> 7, k = i & 127;
  int col0 = k << 1;
  int c = col0 >> 3;
  int cp = (c & ~7) | ((c ^ mrow) & 7);
  size_t pos = ((size_t)mrow << 8) + (cp << 3) + (col0 & 7);
  Sh[pos] = h; Sh[pos + 1] = 0;
  Sm[pos] = m; Sm[pos + 1] = 0;
  Sl[pos] = l; Sl[pos + 1] = 0;
}

// ---------------------------------------------------- GEMM1: OA+STFT+mod ----
// Block = (batch b, 64 frames from f0). A = waveform (OA'd from FR) split into
// 3 swizzled bf16 LDS arrays once. B from global (L2) per-lane. No K-loop
// barriers. Epilogue writes split pre-swizzled S.
__global__ __launch_bounds__(256) void gemm1_k(const float* __restrict__ FR,
    const short* __restrict__ WfH, const short* __restrict__ WfM,
    const short* __restrict__ WfL, const float* __restrict__ x,
    short* __restrict__ Sh, short* __restrict__ Sm, short* __restrict__ Sl) {
  __shared__ __align__(16) short wh[4288], wm[4288], wl[4288];
  int blk = blockIdx.x;
  int b = blk >> 2, f0 = (blk & 3) << 6;
  int tid = threadIdx.x, lane = tid & 63, wv = tid >> 6;
  const float* FRb = FR + ((size_t)b << 16);

  // fused overlap-add -> split3 -> swizzled LDS (chunk q -> q^( (q>>3)&7 ))
  for (int i = tid; i < 4288; i += 256) {
    float s = 0.f;
    if (i < 4286) {
      int t = (f0 << 6) + i;
      int f_hi = t >> 6; if (f_hi > NFRM - 1) f_hi = NFRM - 1;
      int f_lo = (t >= NFFT) ? (((t - NFFT) >> 6) + 1) : 0;
      for (int f = f_lo; f <= f_hi; ++f) s += FRb[(f << 8) + t - (f << 6)];
    }
    short h, m, l2;
    split3(s, &h, &m, &l2);
    int q = i >> 3;
    int qs = (q & ~7) | ((q ^ (q >> 3)) & 7);
    int p = (qs << 3) | (i & 7);
    wh[p] = h; wm[p] = m; wl[p] = l2;
  }

  f32x4 acc[4][4];
#pragma unroll
  for (int i = 0; i < 4; ++i)
#pragma unroll
    for (int jj = 0; jj < 4; ++jj) acc[i][jj] = (f32x4){0.f, 0.f, 0.f, 0.f};

  __syncthreads();

  for (int kc = 0; kc < 8; ++kc) {
    short8 Ah[4], Am[4], Al[4];
#pragma unroll
    for (int mt = 0; mt < 4; ++mt) {
      int frame = (mt << 4) + (lane & 15);
      int q = (frame << 3) + (kc << 2) + (lane >> 4);
      int qs = (q & ~7) | ((q ^ (q >> 3)) & 7);
      Ah[mt] = *(const short8*)&wh[qs << 3];
      Am[mt] = *(const short8*)&wm[qs << 3];
      Al[mt] = *(const short8*)&wl[qs << 3];
    }
#pragma unroll
    for (int nt = 0; nt < 4; ++nt) {
      int ntg = (wv << 2) + nt;
      size_t off = (((size_t)((kc << 4) + ntg) << 6) + lane) << 3;
      short8 bh = *(const short8*)(WfH + off);
      short8 bm = *(const short8*)(WfM + off);
      short8 bl = *(const short8*)(WfL + off);
#pragma unroll
      for (int mt = 0; mt < 4; ++mt) {
        MFMA6(acc[mt][nt], Ah[mt], Am[mt], Al[mt], bh, bm, bl)
      }
    }
  }

  // epilogue: spec = mag * X/|X|, split3, pre-swizzled S write
  int fgl = b * NFRM + f0;
#pragma unroll
  for (int mt = 0; mt < 4; ++mt)
#pragma unroll
    for (int nt = 0; nt < 4; ++nt) {
      int col = (((wv << 2) + nt) << 4) | (lane & 15);
      int bin = col >> 1;
#pragma unroll
      for (int r = 0; r < 4; ++r) {
        int row = (mt << 4) + ((lane >> 4) << 2) + r;
        float v = acc[mt][nt][r];
        float sq = v * v;
        float s2 = sq + __shfl_xor(sq, 1, 64);     // partner lane = re/im mate
        float mg = expf(5.f * (x[(size_t)(fgl + row) * BINS + bin] - 1.f)) * MAXV;
        float o;
        if (s2 == 0.f) o = (col & 1) ? 0.f : mg;   // angle(0)=0
        else o = v * mg * rsqrtf(s2);
        short oh, om, ol;
        split3(o, &oh, &om, &ol);
        int c = col >> 3;
        int cp = (c & ~7) | ((c ^ (f0 + row)) & 7);
        size_t pos = ((size_t)(fgl + row) << 8) + (cp << 3) + (col & 7);
        Sh[pos] = oh; Sm[pos] = om; Sl[pos] = ol;
      }
    }
}

// --------------------------------------------------------- GEMM2: iSTFT -----
// FR[m][n] = sum_k S[m][k]*Wi[k][n]. A staged (split bf16, pre-swizzled
// global -> linear LDS via global_load_lds), double-buffered per kc2 (64 k).
// B from global per-lane. One barrier per kc2.
__global__ __launch_bounds__(256) void gemm2_k(const short* __restrict__ Sh,
    const short* __restrict__ Sm, const short* __restrict__ Sl,
    const short* __restrict__ WiH, const short* __restrict__ WiM,
    const short* __restrict__ WiL, float* __restrict__ FR) {
  __shared__ __align__(16) short AsH[2][4096], AsM[2][4096], AsL[2][4096];
  int row0 = blockIdx.x << 6;
  int tid = threadIdx.x, lane = tid & 63, wv = tid >> 6;

  int r0 = row0 + (tid >> 3);
  int scoff = (tid & 7) << 3;

#define STAGE_A(BUF, KC2)                                                     \
  {                                                                           \
    int o1 = ((KC2) << 6) + scoff;                                            \
    gld16(Sh + ((size_t)r0 << 8) + o1, &AsH[BUF][wv << 9]);                   \
    gld16(Sm + ((size_t)r0 << 8) + o1, &AsM[BUF][wv << 9]);                   \
    gld16(Sl + ((size_t)r0 << 8) + o1, &AsL[BUF][wv << 9]);                   \
    gld16(Sh + ((size_t)(r0 + 32) << 8) + o1, &AsH[BUF][2048 + (wv << 9)]);   \
    gld16(Sm + ((size_t)(r0 + 32) << 8) + o1, &AsM[BUF][2048 + (wv << 9)]);   \
    gld16(Sl + ((size_t)(r0 + 32) << 8) + o1, &AsL[BUF][2048 + (wv << 9)]);   \
  }

  STAGE_A(0, 0)

  f32x4 acc[4][4];
#pragma unroll
  for (int i = 0; i < 4; ++i)
#pragma unroll
    for (int jj = 0; jj < 4; ++jj) acc[i][jj] = (f32x4){0.f, 0.f, 0.f, 0.f};

  __syncthreads();                                  // stage 0 complete

  int buf = 0;
  for (int kc2 = 0; kc2 < 4; ++kc2) {
    if (kc2 < 3) STAGE_A(buf ^ 1, kc2 + 1)          // async, lands in other buf
#pragma unroll
    for (int kh = 0; kh < 2; ++kh) {
      int kc = (kc2 << 1) + kh;
      short8 Ah[4], Am[4], Al[4];
#pragma unroll
      for (int mt = 0; mt < 4; ++mt) {
        int rl = (mt << 4) + (lane & 15);
        int cl = (kh << 2) + (lane >> 4);
        int ls = (cl ^ rl) & 7;
        int base = (rl << 6) + (ls << 3);
        Ah[mt] = *(const short8*)&AsH[buf][base];
        Am[mt] = *(const short8*)&AsM[buf][base];
        Al[mt] = *(const short8*)&AsL[buf][base];
      }
#pragma unroll
      for (int nt = 0; nt < 4; ++nt) {
        int ntg = (wv << 2) + nt;
        size_t off = (((size_t)((kc << 4) + ntg) << 6) + lane) << 3;
        short8 bh = *(const short8*)(WiH + off);
        short8 bm = *(const short8*)(WiM + off);
        short8 bl = *(const short8*)(WiL + off);
#pragma unroll
        for (int mt = 0; mt < 4; ++mt) {
          MFMA6(acc[mt][nt], Ah[mt], Am[mt], Al[mt], bh, bm, bl)
        }
      }
    }
    __syncthreads();                                // stage done + buf free
    buf ^= 1;
  }

#pragma unroll
  for (int mt = 0; mt < 4; ++mt)
#pragma unroll
    for (int nt = 0; nt < 4; ++nt) {
      int col = (((wv << 2) + nt) << 4) | (lane & 15);
#pragma unroll
      for (int r = 0; r < 4; ++r) {
        int row = row0 + (mt << 4) + ((lane >> 4) << 2) + r;
        FR[((size_t)row << 8) + col] = acc[mt][nt][r];
      }
    }
#undef STAGE_A
}

// ------------------------------------------------- reductions (OA fused) ----
__global__ void redmax_k(const float* __restrict__ FR, unsigned* __restrict__ gmax) {
  __shared__ float red[16];
  int b = blockIdx.x;
  const float* FRb = FR + ((size_t)b << 16);
  float v = 0.f;
  for (int t = threadIdx.x; t < OUTL; t += 1024) {
    int f_hi = t >> 6; if (f_hi > NFRM - 1) f_hi = NFRM - 1;
    int f_lo = (t >= NFFT) ? (((t - NFFT) >> 6) + 1) : 0;
    float s = 0.f;
    for (int f = f_lo; f <= f_hi; ++f) s += FRb[(f << 8) + t - (f << 6)];
    v = fmaxf(v, fabsf(s));
  }
#pragma unroll
  for (int o = 32; o > 0; o >>= 1) v = fmaxf(v, __shfl_xor(v, o, 64));
  if ((threadIdx.x & 63) == 0) red[threadIdx.x >> 6] = v;
  __syncthreads();
  if (threadIdx.x < 16) {
    v = red[threadIdx.x];
#pragma unroll
    for (int o = 8; o > 0; o >>= 1) v = fmaxf(v, __shfl_xor(v, o, 16));
    if (threadIdx.x == 0) atomicMax(gmax, __float_as_uint(v));
  }
}

__global__ void out_k(const float* __restrict__ FR, const unsigned* __restrict__ gmax,
                      float* __restrict__ out) {
  int b = blockIdx.y, t = blockIdx.x * 256 + threadIdx.x;   // t < 16384 exact
  const float* FRb = FR + ((size_t)b << 16);
  int f_hi = t >> 6; if (f_hi > NFRM - 1) f_hi = NFRM - 1;
  int f_lo = (t >= NFFT) ? (((t - NFFT) >> 6) + 1) : 0;
  float s = 0.f;
  for (int f = f_lo; f <= f_hi; ++f) s += FRb[(f << 8) + t - (f << 6)];
  float g = __uint_as_float(*gmax);
  out[(size_t)b * AUD + t] = s / g;
}

// ---------------------------------------------------------------- launch ----
extern "C" void kernel_launch(void* const* d_in, const int* in_sizes, int n_in,
                              void* d_out, int out_size, void* d_ws, size_t ws_size,
                              hipStream_t stream) {
  const float* x = (const float*)d_in[0];

  float* FR  = (float*)d_ws;                        // 8,388,608 f = 33.55 MB
  short* Sh  = (short*)(FR + 8388608);              // 8,388,608 sh each (16.78 MB)
  short* Sm  = Sh + 8388608;
  short* Sl  = Sm + 8388608;
  short* WfH = Sl + 8388608;                        // 65536 sh each
  short* WfM = WfH + 65536;
  short* WfL = WfM + 65536;
  short* WiH = WfL + 65536;
  short* WiM = WiH + 65536;
  short* WiL = WiM + 65536;
  unsigned* gmax = (unsigned*)(WiL + 65536);        // total ~84.7 MB

  tables_k<<<256, 256, 0, stream>>>(WfH, WfM, WfL, WiH, WiM, WiL, gmax);
  initS_k<<<16384, 256, 0, stream>>>(x, Sh, Sm, Sl);

  gemm2_k<<<512, 256, 0, stream>>>(Sh, Sm, Sl, WiH, WiM, WiL, FR);  // initial istft

  for (int it = 0; it < GL_ITERS; ++it) {
    gemm1_k<<<512, 256, 0, stream>>>(FR, WfH, WfM, WfL, x, Sh, Sm, Sl);
    gemm2_k<<<512, 256, 0, stream>>>(Sh, Sm, Sl, WiH, WiM, WiL, FR);
  }

  redmax_k<<<B_SZ, 1024, 0, stream>>>(FR, gmax);
  out_k<<<dim3(64, B_SZ), 256, 0, stream>>>(FR, gmax, (float*)d_out);
}

// Round 6
// 2869.517 us; speedup vs baseline: 13.1972x; 1.5925x over previous
//
#include <hip/hip_runtime.h>
#include <math.h>

// Griffin-Lim inversion, fp32-accurate MFMA edition, v2 (occupancy + vector I/O).
// Both DFT GEMMs on v_mfma_f32_16x16x32_bf16 with 3-term bf16 splits (6 MFMAs,
// error ~2^-24 — fp32-grade). 512-thread blocks (8 waves, 2 N-tiles each).
// OA vectorized float4 (FR cols 254/255 are exact zeros). gemm1 epilogue goes
// through an LDS transpose tile -> 16B vectorized S stores, no shfl, 4x fewer expf.

#define B_SZ 128
#define NFRM 256
#define BINS 128
#define NFFT 254
#define OUTL 16574
#define AUD  16384
#define GL_ITERS 50
#define MAXV 69.37411499023438f
#define PI2f 6.2831853071795864f

typedef __attribute__((ext_vector_type(8))) short short8;
typedef __attribute__((ext_vector_type(4))) float f32x4;

__device__ __forceinline__ unsigned short f2bf(float f) {     // RNE f32->bf16
  unsigned u = __float_as_uint(f);
  return (unsigned short)((u + 0x7FFFu + ((u >> 16) & 1u)) >> 16);
}
__device__ __forceinline__ float bf2f(unsigned short h) {
  return __uint_as_float(((unsigned)h) << 16);
}
__device__ __forceinline__ void split3(float v, short* h, short* m, short* l) {
  unsigned short hh = f2bf(v);
  float r1 = v - bf2f(hh);
  unsigned short mm = f2bf(r1);
  float r2 = r1 - bf2f(mm);
  *h = (short)hh; *m = (short)mm; *l = (short)f2bf(r2);
}
__device__ __forceinline__ void gld16(const void* g, void* l) {
  __builtin_amdgcn_global_load_lds(
      (const __attribute__((address_space(1))) unsigned*)g,
      (__attribute__((address_space(3))) unsigned*)l, 16, 0, 0);
}

#define MFMA6(ACC, AH, AM, AL, BH, BM, BL)                                   \
  ACC = __builtin_amdgcn_mfma_f32_16x16x32_bf16(AH, BL, ACC, 0, 0, 0);       \
  ACC = __builtin_amdgcn_mfma_f32_16x16x32_bf16(AM, BM, ACC, 0, 0, 0);       \
  ACC = __builtin_amdgcn_mfma_f32_16x16x32_bf16(AL, BH, ACC, 0, 0, 0);       \
  ACC = __builtin_amdgcn_mfma_f32_16x16x32_bf16(AH, BM, ACC, 0, 0, 0);       \
  ACC = __builtin_amdgcn_mfma_f32_16x16x32_bf16(AM, BH, ACC, 0, 0, 0);       \
  ACC = __builtin_amdgcn_mfma_f32_16x16x32_bf16(AH, BH, ACC, 0, 0, 0);

// ---------------------------------------------------------------- tables ----
// Fragment order: tile (kc,nt): lane l elem j <- W[kc*32+(l>>4)*8+j][nt*16+(l&15)]
__global__ void tables_k(short* __restrict__ WfH, short* __restrict__ WfM,
                         short* __restrict__ WfL, short* __restrict__ WiH,
                         short* __restrict__ WiM, short* __restrict__ WiL,
                         unsigned* __restrict__ gmax) {
  int tid = blockIdx.x * blockDim.x + threadIdx.x;
  if (tid == 0) *gmax = 0u;
  if (tid >= 65536) return;
  int idx = tid;
  int j = idx & 7, l = (idx >> 3) & 63, nt = (idx >> 9) & 15, kc = idx >> 13;
  int krow = kc * 32 + ((l >> 4) << 3) + j;
  int ncol = (nt << 4) + (l & 15);
  float v1 = 0.f;
  if (krow < NFFT) {
    int kk = ncol >> 1;
    int m = (kk * krow) % NFFT;
    float ang = PI2f * (float)m / (float)NFFT;
    float wn = 0.5f - 0.5f * cosf(PI2f * (float)krow / (float)NFFT);
    v1 = wn * ((ncol & 1) ? -sinf(ang) : cosf(ang));
  }
  split3(v1, &WfH[idx], &WfM[idx], &WfL[idx]);
  float v2 = 0.f;
  if (ncol < NFFT) {
    int kk = krow >> 1;
    int m = (kk * ncol) % NFFT;
    float ang = PI2f * (float)m / (float)NFFT;
    float wn = 0.5f - 0.5f * cosf(PI2f * (float)ncol / (float)NFFT);
    float d = 0.f;
    int p = ncol & 63;
    for (int q = 0; q < 4; ++q) {
      int nn = p + 64 * q;
      if (nn < NFFT) { float w = 0.5f - 0.5f * cosf(PI2f * (float)nn / (float)NFFT); d += w * w; }
    }
    float sw = wn / d;
    float ak = (kk == 0 || kk == BINS - 1) ? 1.f : 2.f;
    v2 = sw * (ak / (float)NFFT) * ((krow & 1) ? -sinf(ang) : cosf(ang));
  }
  split3(v2, &WiH[idx], &WiM[idx], &WiL[idx]);
}

// -------------------------------------------------------------- initial S ---
// S rows of 256 bf16; 8-short chunk c of row r stored at (c&~7)|((c^r)&7).
__global__ void initS_k(const float* __restrict__ x, short* __restrict__ Sh,
                        short* __restrict__ Sm, short* __restrict__ Sl) {
  int i = blockIdx.x * 256 + threadIdx.x;
  float v = expf(5.f * (x[i] - 1.f)) * MAXV;
  short h, m, l;
  split3(v, &h, &m, &l);
  int mrow = i >> 7, k = i & 127;
  int col0 = k << 1;
  int c = col0 >> 3;
  int cp = (c & ~7) | ((c ^ mrow) & 7);
  size_t pos = ((size_t)mrow << 8) + (cp << 3) + (col0 & 7);
  Sh[pos] = h; Sh[pos + 1] = 0;
  Sm[pos] = m; Sm[pos + 1] = 0;
  Sl[pos] = l; Sl[pos + 1] = 0;
}

// ---------------------------------------------------- GEMM1: OA+STFT+mod ----
// 512 threads (8 waves). Block = (batch b, 64 frames from f0).
__global__ __launch_bounds__(512) void gemm1_k(const float* __restrict__ FR,
    const short* __restrict__ WfH, const short* __restrict__ WfM,
    const short* __restrict__ WfL, const float* __restrict__ x,
    short* __restrict__ Sh, short* __restrict__ Sm, short* __restrict__ Sl) {
  __shared__ __align__(16) char ldsbuf[25728];     // wh/wm/wl (3*4288 sh) | tr (16x260 f32)
  short* wh = (short*)ldsbuf;
  short* wm = wh + 4288;
  short* wl = wm + 4288;
  float* tr = (float*)ldsbuf;

  int blk = blockIdx.x;
  int b = blk >> 2, f0 = (blk & 3) << 6;
  int tid = threadIdx.x, lane = tid & 63, wv = tid >> 6;
  const float* FRb = FR + ((size_t)b << 16);

  // vectorized fused overlap-add -> split3 -> swizzled bf16 LDS
  for (int i4 = tid; i4 < 1072; i4 += 512) {
    int i = i4 << 2;
    int t = (f0 << 6) + i;
    int ft = t >> 6, cb = t & 63;
    float4 s = make_float4(0.f, 0.f, 0.f, 0.f);
#pragma unroll
    for (int d = 3; d >= 0; --d) {                 // ascending f; extra terms exact 0
      int f = ft - d;
      if (f >= 0 && f <= 255) {
        float4 v = *(const float4*)&FRb[(f << 8) + cb + (d << 6)];
        s.x += v.x; s.y += v.y; s.z += v.z; s.w += v.w;
      }
    }
    if (i == 4284) { s.z = 0.f; s.w = 0.f; }       // beyond 4286: dead (zero B rows)
    short hh[4] __attribute__((aligned(8))), mm[4] __attribute__((aligned(8))),
          ll[4] __attribute__((aligned(8)));
    split3(s.x, &hh[0], &mm[0], &ll[0]);
    split3(s.y, &hh[1], &mm[1], &ll[1]);
    split3(s.z, &hh[2], &mm[2], &ll[2]);
    split3(s.w, &hh[3], &mm[3], &ll[3]);
    int q = i >> 3;
    int qs = (q & ~7) | ((q ^ (q >> 3)) & 7);
    int p = (qs << 3) | (i & 7);
    *(short4*)&wh[p] = *(const short4*)hh;
    *(short4*)&wm[p] = *(const short4*)mm;
    *(short4*)&wl[p] = *(const short4*)ll;
  }

  f32x4 acc[4][2];
#pragma unroll
  for (int i = 0; i < 4; ++i) { acc[i][0] = (f32x4){0,0,0,0}; acc[i][1] = (f32x4){0,0,0,0}; }

  __syncthreads();

  for (int kc = 0; kc < 8; ++kc) {
    short8 Ah[4], Am[4], Al[4];
#pragma unroll
    for (int mt = 0; mt < 4; ++mt) {
      int frame = (mt << 4) + (lane & 15);
      int q = (frame << 3) + (kc << 2) + (lane >> 4);
      int qs = (q & ~7) | ((q ^ (q >> 3)) & 7);
      Ah[mt] = *(const short8*)&wh[qs << 3];
      Am[mt] = *(const short8*)&wm[qs << 3];
      Al[mt] = *(const short8*)&wl[qs << 3];
    }
#pragma unroll
    for (int nt = 0; nt < 2; ++nt) {
      int ntg = (wv << 1) + nt;
      size_t off = (((size_t)((kc << 4) + ntg) << 6) + lane) << 3;
      short8 bh = *(const short8*)(WfH + off);
      short8 bm = *(const short8*)(WfM + off);
      short8 bl = *(const short8*)(WfL + off);
#pragma unroll
      for (int mt = 0; mt < 4; ++mt) {
        MFMA6(acc[mt][nt], Ah[mt], Am[mt], Al[mt], bh, bm, bl)
      }
    }
  }

  // epilogue: 4 phases through LDS transpose tile; mag*X/|X|; vector S stores
  int fgl = b * NFRM + f0;
  for (int mtg = 0; mtg < 4; ++mtg) {
    __syncthreads();                               // tile (aliased) free
#pragma unroll
    for (int nt = 0; nt < 2; ++nt) {
      int colb = ((((wv << 1) + nt) << 4) | (lane & 15));
#pragma unroll
      for (int r = 0; r < 4; ++r) {
        int row = ((lane >> 4) << 2) + r;          // 0..15
        tr[row * 260 + colb] = acc[mtg][nt][r];
      }
    }
    __syncthreads();
    {
      int trow = tid >> 5;                         // 0..15
      int c0 = (tid & 31) << 3;                    // col base
      float4 va = *(const float4*)&tr[trow * 260 + c0];
      float4 vb = *(const float4*)&tr[trow * 260 + c0 + 4];
      int srow = fgl + (mtg << 4) + trow;
      float4 xm = *(const float4*)&x[((size_t)srow << 7) + ((tid & 31) << 2)];
      float vv[8] = {va.x, va.y, va.z, va.w, vb.x, vb.y, vb.z, vb.w};
      short hh[8] __attribute__((aligned(16))), mm[8] __attribute__((aligned(16))),
            ll[8] __attribute__((aligned(16)));
#pragma unroll
      for (int pq = 0; pq < 4; ++pq) {
        float mg = expf(5.f * (((const float*)&xm)[pq] - 1.f)) * MAXV;
        float re = vv[2 * pq], im = vv[2 * pq + 1];
        float s2 = re * re + im * im;
        float oe, oo;
        if (s2 == 0.f) { oe = mg; oo = 0.f; }
        else { float rr = mg * rsqrtf(s2); oe = re * rr; oo = im * rr; }
        split3(oe, &hh[2 * pq], &mm[2 * pq], &ll[2 * pq]);
        split3(oo, &hh[2 * pq + 1], &mm[2 * pq + 1], &ll[2 * pq + 1]);
      }
      int c = tid & 31;
      int cp = (c & ~7) | ((c ^ srow) & 7);
      size_t pos = ((size_t)srow << 8) + (cp << 3);
      *(short8*)&Sh[pos] = *(const short8*)hh;
      *(short8*)&Sm[pos] = *(const short8*)mm;
      *(short8*)&Sl[pos] = *(const short8*)ll;
    }
  }
}

// --------------------------------------------------------- GEMM2: iSTFT -----
// 512 threads (8 waves). FR[m][n] = sum_k S[m][k]*Wi[k][n].
__global__ __launch_bounds__(512) void gemm2_k(const short* __restrict__ Sh,
    const short* __restrict__ Sm, const short* __restrict__ Sl,
    const short* __restrict__ WiH, const short* __restrict__ WiM,
    const short* __restrict__ WiL, float* __restrict__ FR) {
  __shared__ __align__(16) short AsH[2][4096], AsM[2][4096], AsL[2][4096];
  int row0 = blockIdx.x << 6;
  int tid = threadIdx.x, lane = tid & 63, wv = tid >> 6;

  int r0 = row0 + (tid >> 3);
  int scoff = (tid & 7) << 3;

#define STAGE_A(BUF, KC2)                                                     \
  {                                                                           \
    size_t go = ((size_t)r0 << 8) + ((KC2) << 6) + scoff;                     \
    gld16(Sh + go, &AsH[BUF][wv << 9]);                                       \
    gld16(Sm + go, &AsM[BUF][wv << 9]);                                       \
    gld16(Sl + go, &AsL[BUF][wv << 9]);                                       \
  }

  STAGE_A(0, 0)

  f32x4 acc[4][2];
#pragma unroll
  for (int i = 0; i < 4; ++i) { acc[i][0] = (f32x4){0,0,0,0}; acc[i][1] = (f32x4){0,0,0,0}; }

  __syncthreads();

  int buf = 0;
  for (int kc2 = 0; kc2 < 4; ++kc2) {
    if (kc2 < 3) STAGE_A(buf ^ 1, kc2 + 1)
#pragma unroll
    for (int kh = 0; kh < 2; ++kh) {
      int kc = (kc2 << 1) + kh;
      short8 Ah[4], Am[4], Al[4];
#pragma unroll
      for (int mt = 0; mt < 4; ++mt) {
        int rl = (mt << 4) + (lane & 15);
        int cl = (kh << 2) + (lane >> 4);
        int ls = (cl ^ rl) & 7;
        int base = (rl << 6) + (ls << 3);
        Ah[mt] = *(const short8*)&AsH[buf][base];
        Am[mt] = *(const short8*)&AsM[buf][base];
        Al[mt] = *(const short8*)&AsL[buf][base];
      }
#pragma unroll
      for (int nt = 0; nt < 2; ++nt) {
        int ntg = (wv << 1) + nt;
        size_t off = (((size_t)((kc << 4) + ntg) << 6) + lane) << 3;
        short8 bh = *(const short8*)(WiH + off);
        short8 bm = *(const short8*)(WiM + off);
        short8 bl = *(const short8*)(WiL + off);
#pragma unroll
        for (int mt = 0; mt < 4; ++mt) {
          MFMA6(acc[mt][nt], Ah[mt], Am[mt], Al[mt], bh, bm, bl)
        }
      }
    }
    __syncthreads();
    buf ^= 1;
  }

#pragma unroll
  for (int mt = 0; mt < 4; ++mt)
#pragma unroll
    for (int nt = 0; nt < 2; ++nt) {
      int col = ((((wv << 1) + nt) << 4) | (lane & 15));
#pragma unroll
      for (int r = 0; r < 4; ++r) {
        int row = row0 + (mt << 4) + ((lane >> 4) << 2) + r;
        FR[((size_t)row << 8) + col] = acc[mt][nt][r];
      }
    }
#undef STAGE_A
}

// ------------------------------------------------- reductions (OA fused) ----
__global__ void redmax_k(const float* __restrict__ FR, unsigned* __restrict__ gmax) {
  __shared__ float red[16];
  int b = blockIdx.x;
  const float* FRb = FR + ((size_t)b << 16);
  float v = 0.f;
  for (int t = threadIdx.x; t < OUTL; t += 1024) {
    int f_hi = t >> 6; if (f_hi > NFRM - 1) f_hi = NFRM - 1;
    int f_lo = (t >= NFFT) ? (((t - NFFT) >> 6) + 1) : 0;
    float s = 0.f;
    for (int f = f_lo; f <= f_hi; ++f) s += FRb[(f << 8) + t - (f << 6)];
    v = fmaxf(v, fabsf(s));
  }
#pragma unroll
  for (int o = 32; o > 0; o >>= 1) v = fmaxf(v, __shfl_xor(v, o, 64));
  if ((threadIdx.x & 63) == 0) red[threadIdx.x >> 6] = v;
  __syncthreads();
  if (threadIdx.x < 16) {
    v = red[threadIdx.x];
#pragma unroll
    for (int o = 8; o > 0; o >>= 1) v = fmaxf(v, __shfl_xor(v, o, 16));
    if (threadIdx.x == 0) atomicMax(gmax, __float_as_uint(v));
  }
}

__global__ void out_k(const float* __restrict__ FR, const unsigned* __restrict__ gmax,
                      float* __restrict__ out) {
  int b = blockIdx.y, t = blockIdx.x * 256 + threadIdx.x;
  const float* FRb = FR + ((size_t)b << 16);
  int f_hi = t >> 6; if (f_hi > NFRM - 1) f_hi = NFRM - 1;
  int f_lo = (t >= NFFT) ? (((t - NFFT) >> 6) + 1) : 0;
  float s = 0.f;
  for (int f = f_lo; f <= f_hi; ++f) s += FRb[(f << 8) + t - (f << 6)];
  float g = __uint_as_float(*gmax);
  out[(size_t)b * AUD + t] = s / g;
}

// ---------------------------------------------------------------- launch ----
extern "C" void kernel_launch(void* const* d_in, const int* in_sizes, int n_in,
                              void* d_out, int out_size, void* d_ws, size_t ws_size,
                              hipStream_t stream) {
  const float* x = (const float*)d_in[0];

  float* FR  = (float*)d_ws;                        // 8,388,608 f
  short* Sh  = (short*)(FR + 8388608);
  short* Sm  = Sh + 8388608;
  short* Sl  = Sm + 8388608;
  short* WfH = Sl + 8388608;
  short* WfM = WfH + 65536;
  short* WfL = WfM + 65536;
  short* WiH = WfL + 65536;
  short* WiM = WiH + 65536;
  short* WiL = WiM + 65536;
  unsigned* gmax = (unsigned*)(WiL + 65536);        // ~84.7 MB total

  tables_k<<<256, 256, 0, stream>>>(WfH, WfM, WfL, WiH, WiM, WiL, gmax);
  initS_k<<<16384, 256, 0, stream>>>(x, Sh, Sm, Sl);

  gemm2_k<<<512, 512, 0, stream>>>(Sh, Sm, Sl, WiH, WiM, WiL, FR);

  for (int it = 0; it < GL_ITERS; ++it) {
    gemm1_k<<<512, 512, 0, stream>>>(FR, WfH, WfM, WfL, x, Sh, Sm, Sl);
    gemm2_k<<<512, 512, 0, stream>>>(Sh, Sm, Sl, WiH, WiM, WiL, FR);
  }

  redmax_k<<<B_SZ, 1024, 0, stream>>>(FR, gmax);
  out_k<<<dim3(64, B_SZ), 256, 0, stream>>>(FR, gmax, (float*)d_out);
}